// Round 10
// baseline (415.425 us; speedup 1.0000x reference)
//
#include <hip/hip_runtime.h>
#include <stdint.h>

#define E_NUM 8
#define CAP 8192
#define NTOK 32768
#define CDIM 384
#define DFF 1536
#define CNT_PAD 64  // ints between counters -> 256B, separate cache lines

typedef unsigned short u16;
typedef __attribute__((ext_vector_type(8))) short short8;
typedef __attribute__((ext_vector_type(4))) float f32x4;

__device__ inline u16 f2bf(float f) {
    uint32_t u = __builtin_bit_cast(uint32_t, f);
    u += 0x7fffu + ((u >> 16) & 1u);
    return (u16)(u >> 16);
}

__device__ inline void gload_lds16(const void* g, void* l) {
    __builtin_amdgcn_global_load_lds(
        (const __attribute__((address_space(1))) void*)(uintptr_t)g,
        (__attribute__((address_space(3))) void*)(uint32_t)(uintptr_t)l,
        16, 0, 0);
}

// Inline packed-row prefix: 8 L2-hot scalar loads.
__device__ inline void expert_span(const int* __restrict__ cnt, int e,
                                   int& base, int& n_e) {
    base = 0; n_e = 0;
#pragma unroll
    for (int i = 0; i < E_NUM; ++i) {
        int n = min(cnt[i * CNT_PAD], CAP);
        if (i < e) base += (n + 127) & ~127;
        else if (i == e) n_e = n;
    }
}

// ---------------- routing v3 (unchanged from R8; measured ~70us, diagnosis
// pending — its counters surface next round once the fused GEMM drops below it)
#define RT_TOK 64
#define RT_KC 64
#define RT_XS 68

__global__ __launch_bounds__(256, 4) void routing_kernel(
    const float* __restrict__ x, const float* __restrict__ noise,
    const float* __restrict__ w_route, const float* __restrict__ b_route,
    const float* __restrict__ w_noise, const float* __restrict__ b_noise,
    int* __restrict__ cnt, int* __restrict__ list, float* __restrict__ gate,
    u16* __restrict__ xbf)
{
    __shared__ float xs[RT_TOK * RT_XS];
    int tid = threadIdx.x;
    int lane = tid & 63;
    int seg = __builtin_amdgcn_readfirstlane(tid >> 6);
    int tok = tid & 63;
    int t0 = blockIdx.x * RT_TOK;

    int srow = tid >> 4;
    int scol = (tid & 15) * 4;

    float ar[E_NUM], an[E_NUM];
#pragma unroll
    for (int e = 0; e < E_NUM; ++e) { ar[e] = 0.f; an[e] = 0.f; }

    for (int c = 0; c < CDIM / RT_KC; ++c) {
        __syncthreads();
#pragma unroll
        for (int p = 0; p < 4; ++p) {
            int row = p * 16 + srow;
            float4 v = *(const float4*)(x + (size_t)(t0 + row) * CDIM + c * RT_KC + scol);
            *(float4*)&xs[row * RT_XS + scol] = v;
            uint2 b;
            b.x = (uint32_t)f2bf(v.x) | ((uint32_t)f2bf(v.y) << 16);
            b.y = (uint32_t)f2bf(v.z) | ((uint32_t)f2bf(v.w) << 16);
            *(uint2*)(xbf + (size_t)(t0 + row) * CDIM + c * RT_KC + scol) = b;
        }
        __syncthreads();
#pragma unroll
        for (int q = 0; q < 4; ++q) {
            float4 xq = *(const float4*)&xs[tok * RT_XS + seg * 16 + q * 4];
            int kb = c * RT_KC + seg * 16 + q * 4;
#pragma unroll
            for (int jj = 0; jj < 4; ++jj) {
                const float* wrk = w_route + (size_t)(kb + jj) * E_NUM;
                const float* wnk = w_noise + (size_t)(kb + jj) * E_NUM;
                float4 wa = *(const float4*)wrk, wb = *(const float4*)(wrk + 4);
                float4 na = *(const float4*)wnk, nb = *(const float4*)(wnk + 4);
                float xk = (jj == 0) ? xq.x : (jj == 1) ? xq.y : (jj == 2) ? xq.z : xq.w;
                ar[0] += xk * wa.x; ar[1] += xk * wa.y; ar[2] += xk * wa.z; ar[3] += xk * wa.w;
                ar[4] += xk * wb.x; ar[5] += xk * wb.y; ar[6] += xk * wb.z; ar[7] += xk * wb.w;
                an[0] += xk * na.x; an[1] += xk * na.y; an[2] += xk * na.z; an[3] += xk * na.w;
                an[4] += xk * nb.x; an[5] += xk * nb.y; an[6] += xk * nb.z; an[7] += xk * nb.w;
            }
        }
    }
    __syncthreads();
    float* part = xs;
    float* pp = part + (size_t)(seg * 64 + tok) * 16;
    *(f32x4*)&pp[0]  = (f32x4){ar[0], ar[1], ar[2], ar[3]};
    *(f32x4*)&pp[4]  = (f32x4){ar[4], ar[5], ar[6], ar[7]};
    *(f32x4*)&pp[8]  = (f32x4){an[0], an[1], an[2], an[3]};
    *(f32x4*)&pp[12] = (f32x4){an[4], an[5], an[6], an[7]};
    __syncthreads();
    if (seg == 0) {
        int t = t0 + lane;
        float sr[E_NUM], sn[E_NUM];
#pragma unroll
        for (int e = 0; e < E_NUM; ++e) { sr[e] = b_route[e]; sn[e] = b_noise[e]; }
#pragma unroll
        for (int s = 0; s < 4; ++s) {
            const float* q = part + (size_t)(s * 64 + lane) * 16;
#pragma unroll
            for (int e = 0; e < E_NUM; ++e) { sr[e] += q[e]; sn[e] += q[8 + e]; }
        }
        float nz[E_NUM];
        const float* np = noise + (size_t)t * E_NUM;
#pragma unroll
        for (int e = 0; e < E_NUM; ++e) {
            float s = sn[e];
            float sp = fmaxf(s, 0.f) + __logf(1.f + __expf(-fabsf(s)));
            nz[e] = sr[e] + np[e] * sp;
        }
        float v1 = -1e30f; int i1 = 0;
#pragma unroll
        for (int e = 0; e < E_NUM; ++e) if (nz[e] > v1) { v1 = nz[e]; i1 = e; }
        float v2 = -1e30f;
#pragma unroll
        for (int e = 0; e < E_NUM; ++e) if (e != i1 && nz[e] > v2) v2 = nz[e];
        gate[t] = 1.f / (1.f + __expf(v2 - v1));
#pragma unroll
        for (int e = 0; e < E_NUM; ++e) {
            unsigned long long m = __ballot(i1 == e);
            if (m == 0) continue;
            int cnum = __popcll(m);
            int leader = __ffsll((long long)m) - 1;
            int basec = 0;
            if (lane == leader) basec = atomicAdd(&cnt[e * CNT_PAD], cnum);
            basec = __shfl(basec, leader);
            if (i1 == e) {
                int pos = basec + __popcll(m & ((1ull << lane) - 1ull));
                if (pos < CAP) list[e * CAP + pos] = t;
            }
        }
    }
}

// ------------- merged transpose + fp32->bf16 for BOTH weight tensors -------------
__global__ __launch_bounds__(256) void transpose_cvt_kernel(
    const float* __restrict__ w1, u16* __restrict__ W1t,
    const float* __restrict__ w2, u16* __restrict__ W2t)
{
    __shared__ float tile[32][33];
    int z = blockIdx.z;
    const float* in; u16* out; int R, S, r0, c0;
    if (z < E_NUM) {
        in = w1 + (size_t)z * CDIM * DFF;  out = W1t + (size_t)z * CDIM * DFF;
        R = CDIM; S = DFF;
        c0 = blockIdx.x * 32; r0 = blockIdx.y * 32;
    } else {
        in = w2 + (size_t)(z - E_NUM) * DFF * CDIM;
        out = W2t + (size_t)(z - E_NUM) * DFF * CDIM;
        R = DFF; S = CDIM;
        r0 = blockIdx.x * 32; c0 = blockIdx.y * 32;
    }
    int tx = threadIdx.x, ty = threadIdx.y;
#pragma unroll
    for (int i = ty; i < 32; i += 8)
        tile[i][tx] = in[(size_t)(r0 + i) * S + (c0 + tx)];
    __syncthreads();
#pragma unroll
    for (int i = ty; i < 32; i += 8)
        out[(size_t)(c0 + i) * R + (r0 + tx)] = f2bf(tile[tx][i]);
}

// ------------- FUSED FFN1+FFN2 (R9) ---------------------------------------
// R8 post-mortem: every FFN1 schedule lands 66-73us (MfmaUtil ~21%, nothing
// saturated); the invariant is the two-kernel structure with a 200MB Hb HBM
// round-trip. Fusion: per 128-token tile, loop DFF in 12 chunks of 128:
//   GEMM1 chunk (K=384, dbuf+counted-vmcnt pipeline, 8 waves 2Mx4N)
//   -> bias1+relu^2+bf16 into swizzled H_lds (32KB)
//   -> GEMM2 partial (K=128): Y(128x384) accumulates in regs (96 VGPR/lane),
//      W2t B-frags loaded direct from L2 (double-buffered over ks, static idx).
// k-order identical to the split kernels -> bit-identical accumulation.
// 512 thr / 8 waves; LDS 96.5KB -> 1 block/CU; launch_bounds(512,2) caps
// VGPR at 256 so the block's 8 waves co-reside (2/SIMD).
__global__ __launch_bounds__(512, 2) void moe_ffn_kernel(
    const u16* __restrict__ Xbf, const u16* __restrict__ W1t,
    const u16* __restrict__ W2t, const float* __restrict__ b1,
    const float* __restrict__ b2, float* __restrict__ Out,
    const int* __restrict__ cnt, const int* __restrict__ list,
    const float* __restrict__ gate)
{
    int bid = blockIdx.x;
    int xcd = bid & 7, slot = bid >> 3;
    int mglob = xcd + 8 * slot;            // 0..511
    int e = mglob >> 6;
    int m0 = (mglob & 63) * 128;
    int base, n_e;
    expert_span(cnt, e, base, n_e);
    (void)base;
    int pad_e = (n_e + 127) & ~127;
    if (m0 >= pad_e) return;

    __shared__ __align__(16) u16 As[2][128 * 64];   // 32 KB
    __shared__ __align__(16) u16 Bs[2][128 * 64];   // 32 KB
    __shared__ __align__(16) u16 Hs[128 * 128];     // 32 KB
    __shared__ int s_tok[128];

    int tid = threadIdx.x;
    int w = tid >> 6, lane = tid & 63;
    int quad = lane >> 4, l15 = lane & 15;
    int wr = w & 1;                // M-half (64 rows)
    int wc = w >> 1;               // 0..3

    int srow = tid >> 3;           // 0..63 staging row
    int gcol = ((tid & 7) ^ (srow & 7)) * 8;   // pre-swizzled source col

    if (tid < 128) {
        int rr = m0 + tid;
        s_tok[tid] = (rr < n_e) ? list[(size_t)e * CAP + rr] : NTOK;
    }
    __syncthreads();

    const u16* Arow[2];
#pragma unroll
    for (int i = 0; i < 2; ++i)
        Arow[i] = Xbf + (size_t)s_tok[i * 64 + srow] * CDIM;
    const u16* W1e = W1t + (size_t)e * DFF * CDIM;
    const u16* W2e = W2t + (size_t)e * CDIM * DFF;

    // stage one 128x64 K-tile of A and of B(W1 chunk d) into buf
    auto stage = [&](int buf, int d, int kb) {
#pragma unroll
        for (int i = 0; i < 2; ++i) {
            int row = i * 64 + srow;
            gload_lds16(Arow[i] + kb * 64 + gcol, &As[buf][i * 4096 + tid * 8]);
            gload_lds16(W1e + (size_t)(d * 128 + row) * CDIM + kb * 64 + gcol,
                        &Bs[buf][i * 4096 + tid * 8]);
        }
    };

    // Y accumulator: wave (wr,wc) owns rows wr*64..+64, cols wc*96..+96
    f32x4 accY[4][6];
    f32x4 zero = {0.f, 0.f, 0.f, 0.f};
#pragma unroll
    for (int a = 0; a < 4; ++a)
#pragma unroll
        for (int b = 0; b < 6; ++b) accY[a][b] = zero;

    int n0Y = wc * 96;

    stage(0, 0, 0);
    int buf = 0;
    for (int d = 0; d < DFF / 128; ++d) {
        // ---- GEMM1: H(128x128) = Xbf(128x384) * W1chunk^T, 6 K-steps ----
        f32x4 acc1[4][2];
#pragma unroll
        for (int a = 0; a < 4; ++a)
#pragma unroll
            for (int b = 0; b < 2; ++b) acc1[a][b] = zero;

        for (int kb = 0; kb < 6; ++kb) {
            if (kb < 5)            stage(buf ^ 1, d, kb + 1);
            else if (d < 11)       stage(buf ^ 1, d + 1, 0);
            if (kb < 5 || d < 11) { asm volatile("s_waitcnt vmcnt(4)" ::: "memory"); }
            else                  { asm volatile("s_waitcnt vmcnt(0)" ::: "memory"); }
            __builtin_amdgcn_s_barrier();
            __builtin_amdgcn_sched_barrier(0);
#pragma unroll
            for (int h = 0; h < 2; ++h) {
                int pga = ((h * 4 + quad) ^ (l15 & 7)) * 8;
                short8 af[4], bf[2];
#pragma unroll
                for (int t = 0; t < 4; ++t)
                    af[t] = *(const short8*)&As[buf][(wr * 64 + t * 16 + l15) * 64 + pga];
#pragma unroll
                for (int t = 0; t < 2; ++t)
                    bf[t] = *(const short8*)&Bs[buf][(wc * 32 + t * 16 + l15) * 64 + pga];
#pragma unroll
                for (int mt = 0; mt < 4; ++mt)
#pragma unroll
                    for (int nt = 0; nt < 2; ++nt)
                        acc1[mt][nt] = __builtin_amdgcn_mfma_f32_16x16x32_bf16(
                            af[mt], bf[nt], acc1[mt][nt], 0, 0, 0);
            }
            __builtin_amdgcn_sched_barrier(0);
            __builtin_amdgcn_s_barrier();
            __builtin_amdgcn_sched_barrier(0);
            buf ^= 1;
        }

        // ---- H epilogue: bias + relu^2 -> bf16 -> swizzled H_lds ----
#pragma unroll
        for (int nt = 0; nt < 2; ++nt) {
            int colL = wc * 32 + nt * 16 + l15;
            float bb = b1[(size_t)e * DFF + d * 128 + colL];
#pragma unroll
            for (int mt = 0; mt < 4; ++mt) {
                int rowB = wr * 64 + mt * 16 + quad * 4;
#pragma unroll
                for (int r = 0; r < 4; ++r) {
                    float v = acc1[mt][nt][r] + bb;
                    v = fmaxf(v, 0.f);
                    int row = rowB + r;
                    Hs[row * 128 + (colL ^ ((row & 7) << 3))] = f2bf(v * v);
                }
            }
        }
        __builtin_amdgcn_s_barrier();   // H visible to all waves

        // ---- GEMM2 partial: Y += H(128x128) * W2chunk^T (K=128) ----
        // B-frags direct from global (L2-hot W2t slice), double-buffered on ks.
        short8 Bf0[6], Bf1[6];
#pragma unroll
        for (int nf = 0; nf < 6; ++nf)
            Bf0[nf] = *(const short8*)(W2e + (size_t)(n0Y + nf * 16 + l15) * DFF
                                       + d * 128 + 0 * 32 + quad * 8);
#pragma unroll
        for (int ks = 0; ks < 4; ++ks) {
            if (ks < 3) {
                if (ks & 1) {
#pragma unroll
                    for (int nf = 0; nf < 6; ++nf)
                        Bf0[nf] = *(const short8*)(W2e + (size_t)(n0Y + nf * 16 + l15) * DFF
                                                   + d * 128 + (ks + 1) * 32 + quad * 8);
                } else {
#pragma unroll
                    for (int nf = 0; nf < 6; ++nf)
                        Bf1[nf] = *(const short8*)(W2e + (size_t)(n0Y + nf * 16 + l15) * DFF
                                                   + d * 128 + (ks + 1) * 32 + quad * 8);
                }
                asm volatile("s_waitcnt vmcnt(6)" ::: "memory");
            } else {
                asm volatile("s_waitcnt vmcnt(0)" ::: "memory");
            }
            short8 af2[4];
#pragma unroll
            for (int mf = 0; mf < 4; ++mf) {
                int row = wr * 64 + mf * 16 + l15;
                int col = (ks * 32 + quad * 8) ^ ((l15 & 7) << 3);
                af2[mf] = *(const short8*)&Hs[row * 128 + col];
            }
#pragma unroll
            for (int mf = 0; mf < 4; ++mf)
#pragma unroll
                for (int nf = 0; nf < 6; ++nf)
                    accY[mf][nf] = __builtin_amdgcn_mfma_f32_16x16x32_bf16(
                        af2[mf], (ks & 1) ? Bf1[nf] : Bf0[nf], accY[mf][nf], 0, 0, 0);
        }
        // next chunk's step-0 barrier orders H_lds reuse
    }

    // ---- Y epilogue: bias2 + gate, scatter to Out ----
#pragma unroll
    for (int mf = 0; mf < 4; ++mf) {
        int rowB = wr * 64 + mf * 16 + quad * 4;
#pragma unroll
        for (int r = 0; r < 4; ++r) {
            int rowL = rowB + r;
            int rr = m0 + rowL;
            if (rr < n_e) {
                int tok = s_tok[rowL];
                float g = gate[tok];
#pragma unroll
                for (int nf = 0; nf < 6; ++nf) {
                    int col = n0Y + nf * 16 + l15;
                    float v = accY[mf][nf][r] + b2[(size_t)e * CDIM + col];
                    Out[(size_t)tok * CDIM + col] = v * g;
                }
            }
        }
    }
}

extern "C" void kernel_launch(void* const* d_in, const int* in_sizes, int n_in,
                              void* d_out, int out_size, void* d_ws, size_t ws_size,
                              hipStream_t stream)
{
    const float* x       = (const float*)d_in[0];
    const float* noise   = (const float*)d_in[1];
    const float* w_route = (const float*)d_in[2];
    const float* b_route = (const float*)d_in[3];
    const float* w_noise = (const float*)d_in[4];
    const float* b_noise = (const float*)d_in[5];
    const float* w1      = (const float*)d_in[6];
    const float* b1      = (const float*)d_in[7];
    const float* w2      = (const float*)d_in[8];
    const float* b2      = (const float*)d_in[9];
    float* out = (float*)d_out;

    char* ws = (char*)d_ws;
    size_t off = 0;
    auto alloc = [&](size_t bytes) {
        char* p = ws + off;
        off += (bytes + 255) & ~(size_t)255;
        return p;
    };
    int*   cnt  = (int*)alloc((size_t)E_NUM * CNT_PAD * sizeof(int));
    int*   list = (int*)alloc((size_t)E_NUM * CAP * sizeof(int));
    float* gate = (float*)alloc((size_t)NTOK * sizeof(float));
    u16*   W1t  = (u16*)alloc((size_t)E_NUM * DFF * CDIM * 2);
    u16*   W2t  = (u16*)alloc((size_t)E_NUM * CDIM * DFF * 2);
    u16*   Xbf  = (u16*)alloc((size_t)(NTOK + 1) * CDIM * 2);  // +1 zero dummy row

    hipMemsetAsync(cnt, 0, (size_t)E_NUM * CNT_PAD * sizeof(int), stream);
    hipMemsetAsync(Xbf + (size_t)NTOK * CDIM, 0, CDIM * 2, stream);  // dummy row

    routing_kernel<<<NTOK / RT_TOK, 256, 0, stream>>>(x, noise, w_route, b_route,
                                                      w_noise, b_noise, cnt, list, gate, Xbf);
    transpose_cvt_kernel<<<dim3(48, 12, 16), dim3(32, 8), 0, stream>>>(w1, W1t, w2, W2t);

    moe_ffn_kernel<<<512, 512, 0, stream>>>(Xbf, W1t, W2t, b1, b2, out,
                                            cnt, list, gate);
}

// Round 11
// 301.915 us; speedup vs baseline: 1.3760x; 1.3760x over previous
//
#include <hip/hip_runtime.h>
#include <stdint.h>

#define E_NUM 8
#define CAP 8192
#define NTOK 32768
#define CDIM 384
#define DFF 1536
#define CNT_PAD 64  // ints between counters -> 256B, separate cache lines

typedef unsigned short u16;
typedef __attribute__((ext_vector_type(8))) short short8;
typedef __attribute__((ext_vector_type(4))) float f32x4;

__device__ inline u16 f2bf(float f) {
    uint32_t u = __builtin_bit_cast(uint32_t, f);
    u += 0x7fffu + ((u >> 16) & 1u);
    return (u16)(u >> 16);
}

__device__ inline void gload_lds16(const void* g, void* l) {
    __builtin_amdgcn_global_load_lds(
        (const __attribute__((address_space(1))) void*)(uintptr_t)g,
        (__attribute__((address_space(3))) void*)(uint32_t)(uintptr_t)l,
        16, 0, 0);
}

// Inline packed-row prefix: 8 L2-hot scalar loads.
__device__ inline void expert_span(const int* __restrict__ cnt, int e,
                                   int& base, int& n_e) {
    base = 0; n_e = 0;
#pragma unroll
    for (int i = 0; i < E_NUM; ++i) {
        int n = min(cnt[i * CNT_PAD], CAP);
        if (i < e) base += (n + 127) & ~127;
        else if (i == e) n_e = n;
    }
}

// ---------------- routing v4: v3 + weights staged in LDS ----------------
// R8 measured v3 at ~72-74us vs ~15us ideal. Theory: 384 same-address
// global_load_dwordx4 of weights per wave; the 50MB x-stream evicts the
// 24.6KB weight set from the 32KB L1 every chunk -> serial L2 misses in the
// FMA chain. v4: stage w_route/w_noise into LDS once (24KB; total 41KB LDS
// -> 3 blocks/CU) and read via same-address ds_read broadcast (eviction-
// immune). Identical fp32 fma order -> bit-identical routing decisions.
#define RT_TOK 64
#define RT_KC 64
#define RT_XS 68

__global__ __launch_bounds__(256, 3) void routing_kernel(
    const float* __restrict__ x, const float* __restrict__ noise,
    const float* __restrict__ w_route, const float* __restrict__ b_route,
    const float* __restrict__ w_noise, const float* __restrict__ b_noise,
    int* __restrict__ cnt, int* __restrict__ list, float* __restrict__ gate,
    u16* __restrict__ xbf)
{
    __shared__ float xs[RT_TOK * RT_XS];      // 17408 B; partials overlay at end
    __shared__ float ws_r[CDIM * E_NUM];      // 12 KB
    __shared__ float ws_n[CDIM * E_NUM];      // 12 KB
    int tid = threadIdx.x;
    int lane = tid & 63;
    int seg = __builtin_amdgcn_readfirstlane(tid >> 6);
    int tok = tid & 63;
    int t0 = blockIdx.x * RT_TOK;

    // stage weights: 768 float4 each, 3 per thread
#pragma unroll
    for (int i = 0; i < 3; ++i) {
        int idx = tid + i * 256;
        *(float4*)&ws_r[idx * 4] = ((const float4*)w_route)[idx];
        *(float4*)&ws_n[idx * 4] = ((const float4*)w_noise)[idx];
    }

    int srow = tid >> 4;
    int scol = (tid & 15) * 4;

    float ar[E_NUM], an[E_NUM];
#pragma unroll
    for (int e = 0; e < E_NUM; ++e) { ar[e] = 0.f; an[e] = 0.f; }

    for (int c = 0; c < CDIM / RT_KC; ++c) {
        __syncthreads();   // prev chunk consumed; also orders weight staging
#pragma unroll
        for (int p = 0; p < 4; ++p) {
            int row = p * 16 + srow;
            float4 v = *(const float4*)(x + (size_t)(t0 + row) * CDIM + c * RT_KC + scol);
            *(float4*)&xs[row * RT_XS + scol] = v;
            uint2 b;
            b.x = (uint32_t)f2bf(v.x) | ((uint32_t)f2bf(v.y) << 16);
            b.y = (uint32_t)f2bf(v.z) | ((uint32_t)f2bf(v.w) << 16);
            *(uint2*)(xbf + (size_t)(t0 + row) * CDIM + c * RT_KC + scol) = b;
        }
        __syncthreads();
#pragma unroll
        for (int q = 0; q < 4; ++q) {
            float4 xq = *(const float4*)&xs[tok * RT_XS + seg * 16 + q * 4];
            int kb = c * RT_KC + seg * 16 + q * 4;
#pragma unroll
            for (int jj = 0; jj < 4; ++jj) {
                const float* wrk = &ws_r[(kb + jj) * E_NUM];
                const float* wnk = &ws_n[(kb + jj) * E_NUM];
                float4 wa = *(const float4*)wrk, wb = *(const float4*)(wrk + 4);
                float4 na = *(const float4*)wnk, nb = *(const float4*)(wnk + 4);
                float xk = (jj == 0) ? xq.x : (jj == 1) ? xq.y : (jj == 2) ? xq.z : xq.w;
                ar[0] += xk * wa.x; ar[1] += xk * wa.y; ar[2] += xk * wa.z; ar[3] += xk * wa.w;
                ar[4] += xk * wb.x; ar[5] += xk * wb.y; ar[6] += xk * wb.z; ar[7] += xk * wb.w;
                an[0] += xk * na.x; an[1] += xk * na.y; an[2] += xk * na.z; an[3] += xk * na.w;
                an[4] += xk * nb.x; an[5] += xk * nb.y; an[6] += xk * nb.z; an[7] += xk * nb.w;
            }
        }
    }
    __syncthreads();
    float* part = xs;
    float* pp = part + (size_t)(seg * 64 + tok) * 16;
    *(f32x4*)&pp[0]  = (f32x4){ar[0], ar[1], ar[2], ar[3]};
    *(f32x4*)&pp[4]  = (f32x4){ar[4], ar[5], ar[6], ar[7]};
    *(f32x4*)&pp[8]  = (f32x4){an[0], an[1], an[2], an[3]};
    *(f32x4*)&pp[12] = (f32x4){an[4], an[5], an[6], an[7]};
    __syncthreads();
    if (seg == 0) {
        int t = t0 + lane;
        float sr[E_NUM], sn[E_NUM];
#pragma unroll
        for (int e = 0; e < E_NUM; ++e) { sr[e] = b_route[e]; sn[e] = b_noise[e]; }
#pragma unroll
        for (int s = 0; s < 4; ++s) {
            const float* q = part + (size_t)(s * 64 + lane) * 16;
#pragma unroll
            for (int e = 0; e < E_NUM; ++e) { sr[e] += q[e]; sn[e] += q[8 + e]; }
        }
        float nz[E_NUM];
        const float* np = noise + (size_t)t * E_NUM;
#pragma unroll
        for (int e = 0; e < E_NUM; ++e) {
            float s = sn[e];
            float sp = fmaxf(s, 0.f) + __logf(1.f + __expf(-fabsf(s)));
            nz[e] = sr[e] + np[e] * sp;
        }
        float v1 = -1e30f; int i1 = 0;
#pragma unroll
        for (int e = 0; e < E_NUM; ++e) if (nz[e] > v1) { v1 = nz[e]; i1 = e; }
        float v2 = -1e30f;
#pragma unroll
        for (int e = 0; e < E_NUM; ++e) if (e != i1 && nz[e] > v2) v2 = nz[e];
        gate[t] = 1.f / (1.f + __expf(v2 - v1));
#pragma unroll
        for (int e = 0; e < E_NUM; ++e) {
            unsigned long long m = __ballot(i1 == e);
            if (m == 0) continue;
            int cnum = __popcll(m);
            int leader = __ffsll((long long)m) - 1;
            int basec = 0;
            if (lane == leader) basec = atomicAdd(&cnt[e * CNT_PAD], cnum);
            basec = __shfl(basec, leader);
            if (i1 == e) {
                int pos = basec + __popcll(m & ((1ull << lane) - 1ull));
                if (pos < CAP) list[e * CAP + pos] = t;
            }
        }
    }
}

// ------------- merged transpose + fp32->bf16 for BOTH weight tensors -------------
__global__ __launch_bounds__(256) void transpose_cvt_kernel(
    const float* __restrict__ w1, u16* __restrict__ W1t,
    const float* __restrict__ w2, u16* __restrict__ W2t)
{
    __shared__ float tile[32][33];
    int z = blockIdx.z;
    const float* in; u16* out; int R, S, r0, c0;
    if (z < E_NUM) {
        in = w1 + (size_t)z * CDIM * DFF;  out = W1t + (size_t)z * CDIM * DFF;
        R = CDIM; S = DFF;
        c0 = blockIdx.x * 32; r0 = blockIdx.y * 32;
    } else {
        in = w2 + (size_t)(z - E_NUM) * DFF * CDIM;
        out = W2t + (size_t)(z - E_NUM) * DFF * CDIM;
        R = DFF; S = CDIM;
        r0 = blockIdx.x * 32; c0 = blockIdx.y * 32;
    }
    int tx = threadIdx.x, ty = threadIdx.y;
#pragma unroll
    for (int i = ty; i < 32; i += 8)
        tile[i][tx] = in[(size_t)(r0 + i) * S + (c0 + tx)];
    __syncthreads();
#pragma unroll
    for (int i = ty; i < 32; i += 8)
        out[(size_t)(c0 + i) * R + (r0 + tx)] = f2bf(tile[tx][i]);
}

// ------------- bf16 MFMA GEMM (R8 split, reverted after fusion failed R10:
// fused = 254us from L2-thrashed W2 direct loads (FETCH 170MB) + 1 block/CU
// serialized phases. Split keeps 2 blocks/CU cross-block overlap.)
// dbuf LDS + issue-early counted-vmcnt pipeline with raw s_barrier;
// FFN1 A-rows gathered from token-order Xbf via s_tok; FFN1 epilogue
// LDS-bounced to coalesced dwordx4 stores.
template <int KD, int ND, bool FFN1>
__global__ __launch_bounds__(256, 2) void gemm_kernel(
    const u16* __restrict__ A, const u16* __restrict__ Bt,
    const float* __restrict__ bias, u16* __restrict__ H, float* __restrict__ Out,
    const int* __restrict__ cnt, const int* __restrict__ list,
    const float* __restrict__ gate)
{
    constexpr int NT = ND / 128;
    int bid = blockIdx.x;
    int xcd = bid & 7, slot = bid >> 3;
    int n_idx = slot % NT;
    int mglob = xcd + 8 * (slot / NT);     // 0..511
    int e = mglob >> 6;
    int m0 = (mglob & 63) * 128;
    int base, n_e;
    expert_span(cnt, e, base, n_e);
    int pad_e = (n_e + 127) & ~127;
    if (m0 >= pad_e) return;
    const u16* Be = Bt + ((size_t)e * ND + (size_t)n_idx * 128) * KD;

    __shared__ __align__(16) u16 As[2][128 * 64];
    __shared__ __align__(16) u16 Bs[2][128 * 64];
    __shared__ int s_tok[128];

    int tid = threadIdx.x;
    int w = tid >> 6, lane = tid & 63;
    int quad = lane >> 4, l15 = lane & 15;
    int wr = w & 1, wc = w >> 1;

    int srow = tid >> 3;
    int gcol = ((tid & 7) ^ ((tid >> 3) & 7)) * 8;

    if (FFN1) {
        if (tid < 128) {
            int rr = m0 + tid;
            s_tok[tid] = (rr < n_e) ? list[(size_t)e * CAP + rr] : NTOK;
        }
        __syncthreads();
    }
    const u16* Arow[4];
#pragma unroll
    for (int i = 0; i < 4; ++i) {
        int row = i * 32 + srow;
        if (FFN1) Arow[i] = A + (size_t)s_tok[row] * KD;
        else      Arow[i] = A + (size_t)(base + m0 + row) * KD;
    }

    auto stage = [&](int buf, int kb) {
#pragma unroll
        for (int i = 0; i < 4; ++i) {
            gload_lds16(Arow[i] + kb * 64 + gcol, &As[buf][i * 2048 + tid * 8]);
            gload_lds16(Be + (size_t)(i * 32 + srow) * KD + kb * 64 + gcol,
                        &Bs[buf][i * 2048 + tid * 8]);
        }
    };

    f32x4 acc[4][4];
    f32x4 zero = {0.f, 0.f, 0.f, 0.f};
#pragma unroll
    for (int a = 0; a < 4; ++a)
#pragma unroll
        for (int b = 0; b < 4; ++b) acc[a][b] = zero;

    constexpr int NK = KD / 64;
    stage(0, 0);
#pragma unroll 2
    for (int kb = 0; kb < NK; ++kb) {
        const int cur = kb & 1;
        if (kb + 1 < NK) {
            stage(cur ^ 1, kb + 1);                     // issue next tile early
            asm volatile("s_waitcnt vmcnt(8)" ::: "memory");  // wait CURRENT 8 only
        } else {
            asm volatile("s_waitcnt vmcnt(0)" ::: "memory");
        }
        __builtin_amdgcn_s_barrier();
        __builtin_amdgcn_sched_barrier(0);
#pragma unroll
        for (int h = 0; h < 2; ++h) {
            int pga = (((h * 4 + quad) ^ (l15 & 7))) * 8;  // lane-constant per h
            short8 af[4], bf[4];
#pragma unroll
            for (int t = 0; t < 4; ++t) {
                af[t] = *(const short8*)&As[cur][(wr * 64 + t * 16 + l15) * 64 + pga];
                bf[t] = *(const short8*)&Bs[cur][(wc * 64 + t * 16 + l15) * 64 + pga];
            }
#pragma unroll
            for (int mt = 0; mt < 4; ++mt)
#pragma unroll
                for (int nt = 0; nt < 4; ++nt)
                    acc[mt][nt] = __builtin_amdgcn_mfma_f32_16x16x32_bf16(
                        af[mt], bf[nt], acc[mt][nt], 0, 0, 0);
        }
        __builtin_amdgcn_sched_barrier(0);
        __builtin_amdgcn_s_barrier();
        __builtin_amdgcn_sched_barrier(0);
    }

    int n0 = n_idx * 128;
    if (FFN1) {
        // --- LDS-bounce epilogue: frags -> swizzled LDS -> coalesced 16B stores
        u16* Hs = (u16*)&As[0][0];   // 32 KB (both dbuf halves), done with K-loop
#pragma unroll
        for (int mt = 0; mt < 4; ++mt) {
            int rowL = wr * 64 + mt * 16 + quad * 4;
#pragma unroll
            for (int nt = 0; nt < 4; ++nt) {
                int colL = wc * 64 + nt * 16 + l15;
                float b = bias[(size_t)e * ND + n0 + colL];
#pragma unroll
                for (int r = 0; r < 4; ++r) {
                    float v = acc[mt][nt][r] + b;
                    v = fmaxf(v, 0.f);
                    int row = rowL + r;
                    Hs[row * 128 + (colL ^ ((row & 7) << 3))] = f2bf(v * v);
                }
            }
        }
        __syncthreads();
        u16* He = H + (size_t)(base + m0) * ND + n0;
#pragma unroll
        for (int j = 0; j < 8; ++j) {
            int idx = tid + j * 256;          // 16B units of the 32KB tile
            int row = idx >> 4;
            int c8 = (idx & 15) * 8;          // u16 col offset, 8-aligned
            *(f32x4*)(He + (size_t)row * ND + c8) =
                *(const f32x4*)(Hs + row * 128 + (c8 ^ ((row & 7) << 3)));
        }
    } else {
#pragma unroll
        for (int mt = 0; mt < 4; ++mt) {
            int rowL = wr * 64 + mt * 16 + quad * 4;
#pragma unroll
            for (int r = 0; r < 4; ++r) {
                int rr = m0 + rowL + r;
                if (rr < n_e) {
                    int tok = list[(size_t)e * CAP + rr];
                    float g = gate[tok];
#pragma unroll
                    for (int nt = 0; nt < 4; ++nt) {
                        int col = n0 + wc * 64 + nt * 16 + l15;
                        float v = acc[mt][nt][r] + bias[(size_t)e * ND + col];
                        Out[(size_t)tok * CDIM + col] = v * g;
                    }
                }
            }
        }
    }
}

extern "C" void kernel_launch(void* const* d_in, const int* in_sizes, int n_in,
                              void* d_out, int out_size, void* d_ws, size_t ws_size,
                              hipStream_t stream)
{
    const float* x       = (const float*)d_in[0];
    const float* noise   = (const float*)d_in[1];
    const float* w_route = (const float*)d_in[2];
    const float* b_route = (const float*)d_in[3];
    const float* w_noise = (const float*)d_in[4];
    const float* b_noise = (const float*)d_in[5];
    const float* w1      = (const float*)d_in[6];
    const float* b1      = (const float*)d_in[7];
    const float* w2      = (const float*)d_in[8];
    const float* b2      = (const float*)d_in[9];
    float* out = (float*)d_out;

    char* ws = (char*)d_ws;
    size_t off = 0;
    auto alloc = [&](size_t bytes) {
        char* p = ws + off;
        off += (bytes + 255) & ~(size_t)255;
        return p;
    };
    int*   cnt  = (int*)alloc((size_t)E_NUM * CNT_PAD * sizeof(int));
    int*   list = (int*)alloc((size_t)E_NUM * CAP * sizeof(int));
    float* gate = (float*)alloc((size_t)NTOK * sizeof(float));
    u16*   W1t  = (u16*)alloc((size_t)E_NUM * DFF * CDIM * 2);
    u16*   W2t  = (u16*)alloc((size_t)E_NUM * CDIM * DFF * 2);

    u16* Xbf = (u16*)alloc((size_t)(NTOK + 1) * CDIM * 2);  // +1 zero dummy row
    size_t rows = NTOK + E_NUM * 128;  // packed-row bound
    u16* Hb = (u16*)alloc(rows * DFF * 2);

    hipMemsetAsync(cnt, 0, (size_t)E_NUM * CNT_PAD * sizeof(int), stream);
    hipMemsetAsync(Xbf + (size_t)NTOK * CDIM, 0, CDIM * 2, stream);  // dummy row

    routing_kernel<<<NTOK / RT_TOK, 256, 0, stream>>>(x, noise, w_route, b_route,
                                                      w_noise, b_noise, cnt, list, gate, Xbf);
    transpose_cvt_kernel<<<dim3(48, 12, 16), dim3(32, 8), 0, stream>>>(w1, W1t, w2, W2t);

    gemm_kernel<CDIM, DFF, true><<<dim3((DFF / 128) * 512), 256, 0, stream>>>(
        Xbf, W1t, b1, Hb, nullptr, cnt, list, nullptr);
    gemm_kernel<DFF, CDIM, false><<<dim3((CDIM / 128) * 512), 256, 0, stream>>>(
        Hb, W2t, b2, nullptr, out, cnt, list, gate);
}

// Round 12
// 301.477 us; speedup vs baseline: 1.3780x; 1.0015x over previous
//
#include <hip/hip_runtime.h>
#include <stdint.h>

#define E_NUM 8
#define CAP 8192
#define NTOK 32768
#define CDIM 384
#define DFF 1536
#define CNT_PAD 64  // ints between counters -> 256B, separate cache lines

typedef unsigned short u16;
typedef __attribute__((ext_vector_type(8))) short short8;
typedef __attribute__((ext_vector_type(4))) float f32x4;

__device__ inline u16 f2bf(float f) {
    uint32_t u = __builtin_bit_cast(uint32_t, f);
    u += 0x7fffu + ((u >> 16) & 1u);
    return (u16)(u >> 16);
}

__device__ inline void gload_lds16(const void* g, void* l) {
    __builtin_amdgcn_global_load_lds(
        (const __attribute__((address_space(1))) void*)(uintptr_t)g,
        (__attribute__((address_space(3))) void*)(uint32_t)(uintptr_t)l,
        16, 0, 0);
}

// Inline packed-row prefix: 8 L2-hot scalar loads.
__device__ inline void expert_span(const int* __restrict__ cnt, int e,
                                   int& base, int& n_e) {
    base = 0; n_e = 0;
#pragma unroll
    for (int i = 0; i < E_NUM; ++i) {
        int n = min(cnt[i * CNT_PAD], CAP);
        if (i < e) base += (n + 127) & ~127;
        else if (i == e) n_e = n;
    }
}

// ---------------- FUSED routing + weight-transpose (R12) ----------------
// R11 post-mortem: routing plateaus ~70us across v2/v3/v4 (no single pipe
// explains it) and ~50-70us of the 302 total is launch gaps over 6 dispatches.
// Fuse: blocks 0..511 run routing v4; blocks 512.. run the transpose. The
// BW-bound transpose overlaps the compute-bound routing (no shared data);
// FFN1 waits on both via stream order anyway.
#define RT_TOK 64
#define RT_KC 64
#define RT_XS 68
#define RT_BLOCKS (NTOK / RT_TOK)          // 512
#define TR_BLOCKS (48 * 12 * 16)           // 9216

__global__ __launch_bounds__(256, 3) void route_prep_kernel(
    const float* __restrict__ x, const float* __restrict__ noise,
    const float* __restrict__ w_route, const float* __restrict__ b_route,
    const float* __restrict__ w_noise, const float* __restrict__ b_noise,
    int* __restrict__ cnt, int* __restrict__ list, float* __restrict__ gate,
    u16* __restrict__ xbf,
    const float* __restrict__ w1, u16* __restrict__ W1t,
    const float* __restrict__ w2, u16* __restrict__ W2t)
{
    __shared__ float xs[RT_TOK * RT_XS];      // 17408 B (routing)
    __shared__ float ws_r[CDIM * E_NUM];      // 12 KB (routing)
    __shared__ float ws_n[CDIM * E_NUM];      // 12 KB (routing)
    __shared__ float tile[32][33];            // 4.2 KB (transpose)
    int tid = threadIdx.x;
    int bid = blockIdx.x;

    if (bid >= RT_BLOCKS) {
        // ---------------- transpose role ----------------
        int b = bid - RT_BLOCKS;
        int z = b / 576;            // 48*12
        int rem = b % 576;
        int by = rem / 48, bx = rem % 48;
        const float* in; u16* out; int S, r0, c0;
        if (z < E_NUM) {
            in = w1 + (size_t)z * CDIM * DFF;  out = W1t + (size_t)z * CDIM * DFF;
            S = DFF;   // R = CDIM
            c0 = bx * 32; r0 = by * 32;
        } else {
            in = w2 + (size_t)(z - E_NUM) * DFF * CDIM;
            out = W2t + (size_t)(z - E_NUM) * DFF * CDIM;
            S = CDIM;  // R = DFF
            r0 = bx * 32; c0 = by * 32;
        }
        int R = (z < E_NUM) ? CDIM : DFF;
        int tx = tid & 31, ty = tid >> 5;
#pragma unroll
        for (int i = ty; i < 32; i += 8)
            tile[i][tx] = in[(size_t)(r0 + i) * S + (c0 + tx)];
        __syncthreads();
#pragma unroll
        for (int i = ty; i < 32; i += 8)
            out[(size_t)(c0 + i) * R + (r0 + tx)] = f2bf(tile[tx][i]);
        return;
    }

    // ---------------- routing role (v4 body) ----------------
    int lane = tid & 63;
    int seg = __builtin_amdgcn_readfirstlane(tid >> 6);
    int tok = tid & 63;
    int t0 = bid * RT_TOK;

#pragma unroll
    for (int i = 0; i < 3; ++i) {
        int idx = tid + i * 256;
        *(float4*)&ws_r[idx * 4] = ((const float4*)w_route)[idx];
        *(float4*)&ws_n[idx * 4] = ((const float4*)w_noise)[idx];
    }

    int srow = tid >> 4;
    int scol = (tid & 15) * 4;

    float ar[E_NUM], an[E_NUM];
#pragma unroll
    for (int e = 0; e < E_NUM; ++e) { ar[e] = 0.f; an[e] = 0.f; }

    for (int c = 0; c < CDIM / RT_KC; ++c) {
        __syncthreads();
#pragma unroll
        for (int p = 0; p < 4; ++p) {
            int row = p * 16 + srow;
            float4 v = *(const float4*)(x + (size_t)(t0 + row) * CDIM + c * RT_KC + scol);
            *(float4*)&xs[row * RT_XS + scol] = v;
            uint2 b;
            b.x = (uint32_t)f2bf(v.x) | ((uint32_t)f2bf(v.y) << 16);
            b.y = (uint32_t)f2bf(v.z) | ((uint32_t)f2bf(v.w) << 16);
            *(uint2*)(xbf + (size_t)(t0 + row) * CDIM + c * RT_KC + scol) = b;
        }
        __syncthreads();
#pragma unroll
        for (int q = 0; q < 4; ++q) {
            float4 xq = *(const float4*)&xs[tok * RT_XS + seg * 16 + q * 4];
            int kb = c * RT_KC + seg * 16 + q * 4;
#pragma unroll
            for (int jj = 0; jj < 4; ++jj) {
                const float* wrk = &ws_r[(kb + jj) * E_NUM];
                const float* wnk = &ws_n[(kb + jj) * E_NUM];
                float4 wa = *(const float4*)wrk, wb = *(const float4*)(wrk + 4);
                float4 na = *(const float4*)wnk, nb = *(const float4*)(wnk + 4);
                float xk = (jj == 0) ? xq.x : (jj == 1) ? xq.y : (jj == 2) ? xq.z : xq.w;
                ar[0] += xk * wa.x; ar[1] += xk * wa.y; ar[2] += xk * wa.z; ar[3] += xk * wa.w;
                ar[4] += xk * wb.x; ar[5] += xk * wb.y; ar[6] += xk * wb.z; ar[7] += xk * wb.w;
                an[0] += xk * na.x; an[1] += xk * na.y; an[2] += xk * na.z; an[3] += xk * na.w;
                an[4] += xk * nb.x; an[5] += xk * nb.y; an[6] += xk * nb.z; an[7] += xk * nb.w;
            }
        }
    }
    __syncthreads();
    float* part = xs;
    float* pp = part + (size_t)(seg * 64 + tok) * 16;
    *(f32x4*)&pp[0]  = (f32x4){ar[0], ar[1], ar[2], ar[3]};
    *(f32x4*)&pp[4]  = (f32x4){ar[4], ar[5], ar[6], ar[7]};
    *(f32x4*)&pp[8]  = (f32x4){an[0], an[1], an[2], an[3]};
    *(f32x4*)&pp[12] = (f32x4){an[4], an[5], an[6], an[7]};
    __syncthreads();
    if (seg == 0) {
        int t = t0 + lane;
        float sr[E_NUM], sn[E_NUM];
#pragma unroll
        for (int e = 0; e < E_NUM; ++e) { sr[e] = b_route[e]; sn[e] = b_noise[e]; }
#pragma unroll
        for (int s = 0; s < 4; ++s) {
            const float* q = part + (size_t)(s * 64 + lane) * 16;
#pragma unroll
            for (int e = 0; e < E_NUM; ++e) { sr[e] += q[e]; sn[e] += q[8 + e]; }
        }
        float nz[E_NUM];
        const float* np = noise + (size_t)t * E_NUM;
#pragma unroll
        for (int e = 0; e < E_NUM; ++e) {
            float s = sn[e];
            float sp = fmaxf(s, 0.f) + __logf(1.f + __expf(-fabsf(s)));
            nz[e] = sr[e] + np[e] * sp;
        }
        float v1 = -1e30f; int i1 = 0;
#pragma unroll
        for (int e = 0; e < E_NUM; ++e) if (nz[e] > v1) { v1 = nz[e]; i1 = e; }
        float v2 = -1e30f;
#pragma unroll
        for (int e = 0; e < E_NUM; ++e) if (e != i1 && nz[e] > v2) v2 = nz[e];
        gate[t] = 1.f / (1.f + __expf(v2 - v1));
#pragma unroll
        for (int e = 0; e < E_NUM; ++e) {
            unsigned long long m = __ballot(i1 == e);
            if (m == 0) continue;
            int cnum = __popcll(m);
            int leader = __ffsll((long long)m) - 1;
            int basec = 0;
            if (lane == leader) basec = atomicAdd(&cnt[e * CNT_PAD], cnum);
            basec = __shfl(basec, leader);
            if (i1 == e) {
                int pos = basec + __popcll(m & ((1ull << lane) - 1ull));
                if (pos < CAP) list[e * CAP + pos] = t;
            }
        }
    }
}

// ------------- bf16 MFMA GEMM, 128x128 tile, BK=64 — R12: 512 threads -------
// R11: 4 schedules all land 66-74us with MfmaUtil ~21%, VALUBusy ~25% — both
// pipes half-idle at 8 waves/CU. This round: 8 waves/block (2M x 4N wave grid,
// 64x32 per wave, acc[4][2]) -> 16 waves/CU at the same 2 blocks/CU; K-order
// and fragment mapping unchanged -> bit-identical accumulation.
// FFN1 pad rows read a zeroed dummy row (s_tok = -1).
template <int KD, int ND, bool FFN1>
__global__ __launch_bounds__(512, 4) void gemm_kernel(
    const u16* __restrict__ A, const u16* __restrict__ Bt,
    const float* __restrict__ bias, u16* __restrict__ H, float* __restrict__ Out,
    const int* __restrict__ cnt, const int* __restrict__ list,
    const float* __restrict__ gate, const u16* __restrict__ dummy)
{
    constexpr int NT = ND / 128;
    int bid = blockIdx.x;
    int xcd = bid & 7, slot = bid >> 3;
    int n_idx = slot % NT;
    int mglob = xcd + 8 * (slot / NT);     // 0..511
    int e = mglob >> 6;
    int m0 = (mglob & 63) * 128;
    int base, n_e;
    expert_span(cnt, e, base, n_e);
    int pad_e = (n_e + 127) & ~127;
    if (m0 >= pad_e) return;
    const u16* Be = Bt + ((size_t)e * ND + (size_t)n_idx * 128) * KD;

    __shared__ __align__(16) u16 As[2][128 * 64];
    __shared__ __align__(16) u16 Bs[2][128 * 64];
    __shared__ int s_tok[128];

    int tid = threadIdx.x;
    int w = tid >> 6, lane = tid & 63;
    int quad = lane >> 4, l15 = lane & 15;
    int wr = w & 1;            // M half (64 rows)
    int wc = w >> 1;           // N quarter (32 cols)

    int srow = tid >> 3;       // 0..63
    int gcol = ((tid & 7) ^ (srow & 7)) * 8;

    if (FFN1) {
        if (tid < 128) {
            int rr = m0 + tid;
            s_tok[tid] = (rr < n_e) ? list[(size_t)e * CAP + rr] : -1;
        }
        __syncthreads();
    }
    const u16* Arow[2];
#pragma unroll
    for (int i = 0; i < 2; ++i) {
        int row = i * 64 + srow;
        if (FFN1) {
            int s = s_tok[row];
            Arow[i] = (s >= 0) ? A + (size_t)s * KD : dummy;
        } else {
            Arow[i] = A + (size_t)(base + m0 + row) * KD;
        }
    }

    auto stage = [&](int buf, int kb) {
#pragma unroll
        for (int i = 0; i < 2; ++i) {
            gload_lds16(Arow[i] + kb * 64 + gcol, &As[buf][i * 4096 + tid * 8]);
            gload_lds16(Be + (size_t)(i * 64 + srow) * KD + kb * 64 + gcol,
                        &Bs[buf][i * 4096 + tid * 8]);
        }
    };

    f32x4 acc[4][2];
    f32x4 zero = {0.f, 0.f, 0.f, 0.f};
#pragma unroll
    for (int a = 0; a < 4; ++a)
#pragma unroll
        for (int b = 0; b < 2; ++b) acc[a][b] = zero;

    constexpr int NK = KD / 64;
    stage(0, 0);
#pragma unroll 2
    for (int kb = 0; kb < NK; ++kb) {
        const int cur = kb & 1;
        if (kb + 1 < NK) {
            stage(cur ^ 1, kb + 1);                     // issue next tile early
            asm volatile("s_waitcnt vmcnt(4)" ::: "memory");  // wait CURRENT 4 only
        } else {
            asm volatile("s_waitcnt vmcnt(0)" ::: "memory");
        }
        __builtin_amdgcn_s_barrier();
        __builtin_amdgcn_sched_barrier(0);
#pragma unroll
        for (int h = 0; h < 2; ++h) {
            int pga = ((h * 4 + quad) ^ (l15 & 7)) * 8;  // lane-constant per h
            short8 af[4], bf[2];
#pragma unroll
            for (int t = 0; t < 4; ++t)
                af[t] = *(const short8*)&As[cur][(wr * 64 + t * 16 + l15) * 64 + pga];
#pragma unroll
            for (int t = 0; t < 2; ++t)
                bf[t] = *(const short8*)&Bs[cur][(wc * 32 + t * 16 + l15) * 64 + pga];
#pragma unroll
            for (int mt = 0; mt < 4; ++mt)
#pragma unroll
                for (int nt = 0; nt < 2; ++nt)
                    acc[mt][nt] = __builtin_amdgcn_mfma_f32_16x16x32_bf16(
                        af[mt], bf[nt], acc[mt][nt], 0, 0, 0);
        }
        __builtin_amdgcn_sched_barrier(0);
        __builtin_amdgcn_s_barrier();
        __builtin_amdgcn_sched_barrier(0);
    }

    int n0 = n_idx * 128;
    if (FFN1) {
        // --- LDS-bounce epilogue: frags -> swizzled LDS -> coalesced 16B stores
        u16* Hs = (u16*)&As[0][0];   // 32 KB (both dbuf halves), done with K-loop
#pragma unroll
        for (int mt = 0; mt < 4; ++mt) {
            int rowL = wr * 64 + mt * 16 + quad * 4;
#pragma unroll
            for (int nt = 0; nt < 2; ++nt) {
                int colL = wc * 32 + nt * 16 + l15;
                float b = bias[(size_t)e * ND + n0 + colL];
#pragma unroll
                for (int r = 0; r < 4; ++r) {
                    float v = acc[mt][nt][r] + b;
                    v = fmaxf(v, 0.f);
                    int row = rowL + r;
                    Hs[row * 128 + (colL ^ ((row & 7) << 3))] = f2bf(v * v);
                }
            }
        }
        __syncthreads();
        u16* He = H + (size_t)(base + m0) * ND + n0;
#pragma unroll
        for (int j = 0; j < 4; ++j) {
            int idx = tid + j * 512;          // 16B units of the 32KB tile
            int row = idx >> 4;
            int c8 = (idx & 15) * 8;          // u16 col offset, 8-aligned
            *(f32x4*)(He + (size_t)row * ND + c8) =
                *(const f32x4*)(Hs + row * 128 + (c8 ^ ((row & 7) << 3)));
        }
    } else {
#pragma unroll
        for (int mt = 0; mt < 4; ++mt) {
            int rowL = wr * 64 + mt * 16 + quad * 4;
#pragma unroll
            for (int r = 0; r < 4; ++r) {
                int rr = m0 + rowL + r;
                if (rr < n_e) {
                    int tok = list[(size_t)e * CAP + rr];
                    float g = gate[tok];
#pragma unroll
                    for (int nt = 0; nt < 2; ++nt) {
                        int col = n0 + wc * 32 + nt * 16 + l15;
                        float v = acc[mt][nt][r] + bias[(size_t)e * ND + col];
                        Out[(size_t)tok * CDIM + col] = v * g;
                    }
                }
            }
        }
    }
}

extern "C" void kernel_launch(void* const* d_in, const int* in_sizes, int n_in,
                              void* d_out, int out_size, void* d_ws, size_t ws_size,
                              hipStream_t stream)
{
    const float* x       = (const float*)d_in[0];
    const float* noise   = (const float*)d_in[1];
    const float* w_route = (const float*)d_in[2];
    const float* b_route = (const float*)d_in[3];
    const float* w_noise = (const float*)d_in[4];
    const float* b_noise = (const float*)d_in[5];
    const float* w1      = (const float*)d_in[6];
    const float* b1      = (const float*)d_in[7];
    const float* w2      = (const float*)d_in[8];
    const float* b2      = (const float*)d_in[9];
    float* out = (float*)d_out;

    char* ws = (char*)d_ws;
    size_t off = 0;
    auto alloc = [&](size_t bytes) {
        char* p = ws + off;
        off += (bytes + 255) & ~(size_t)255;
        return p;
    };
    // cnt (2048B) and dummy row (768B) are contiguous -> ONE memset covers both
    int*   cnt   = (int*)alloc((size_t)E_NUM * CNT_PAD * sizeof(int));
    u16*   dummy = (u16*)alloc((size_t)CDIM * 2);
    int*   list  = (int*)alloc((size_t)E_NUM * CAP * sizeof(int));
    float* gate  = (float*)alloc((size_t)NTOK * sizeof(float));
    u16*   W1t   = (u16*)alloc((size_t)E_NUM * DFF * CDIM * 2);
    u16*   W2t   = (u16*)alloc((size_t)E_NUM * CDIM * DFF * 2);
    u16*   Xbf   = (u16*)alloc((size_t)NTOK * CDIM * 2);
    size_t rows = NTOK + E_NUM * 128;  // packed-row bound
    u16*   Hb    = (u16*)alloc(rows * DFF * 2);

    hipMemsetAsync(ws, 0, (size_t)E_NUM * CNT_PAD * sizeof(int) + CDIM * 2, stream);

    route_prep_kernel<<<RT_BLOCKS + TR_BLOCKS, 256, 0, stream>>>(
        x, noise, w_route, b_route, w_noise, b_noise, cnt, list, gate, Xbf,
        w1, W1t, w2, W2t);

    gemm_kernel<CDIM, DFF, true><<<dim3((DFF / 128) * 512), 512, 0, stream>>>(
        Xbf, W1t, b1, Hb, nullptr, cnt, list, nullptr, dummy);
    gemm_kernel<DFF, CDIM, false><<<dim3((CDIM / 128) * 512), 512, 0, stream>>>(
        Hb, W2t, b2, nullptr, out, cnt, list, gate, nullptr);
}